// Round 5
// baseline (508.050 us; speedup 1.0000x reference)
//
#include <hip/hip_runtime.h>

// Exact-binned COO segment-sum, bucket-major, single-u32 payload:
//   payload = (float_bits(p) & ~8191) | (local_row & 8191), bucket = row>>13
//
// Pipeline (5 stream ops):
//   memsetAsync(ctrl 4KB)
//   precount  : exact per-bucket counts; LAST BLOCK does the exclusive scan
//               (starts) + cursor init (device-atomic done-counter)
//   phaseA    : per-4096-nnz chunk: issue cols/rows/16 x-gathers/vals EARLY,
//               raw lgkm-only barriers (no vmcnt drain) so histogram+scan
//               overlap gather latency; LDS counting sort; coalesced
//               run-flush into bucket-major g_w
//   phaseB    : 2 blocks per bucket (halved regions), uint4 reads, LDS f32
//               accumulate, plain store of partial accum into axh[h] slab
//   reduce    : axh0+axh1 -> proj -> inf-norm; LAST BLOCK finalizes out
//
// ctrl (u32): [0..255] hist | [256..511] starts | [512..767] cursors |
//             [768..769] maxslots | [770] done_precount | [771] done_reduce
// ws: ctrl 4KB | g_w u32[nnz] | axh f32[2 * NB * BUCKW]

#define CHUNK 4096
#define BUCKW 8192
#define KPT 16

// lgkm-only barrier: makes LDS ops visible without draining vmcnt (gathers
// stay in flight across it).
#define LBAR() do { \
    asm volatile("s_waitcnt lgkmcnt(0)" ::: "memory"); \
    __builtin_amdgcn_s_barrier(); \
    asm volatile("" ::: "memory"); \
} while (0)

__global__ __launch_bounds__(256) void precount_kernel(
    const int* __restrict__ rows, unsigned int* __restrict__ ctrl, int nnz)
{
    __shared__ unsigned int lh[256];
    __shared__ unsigned int wsum[4];
    __shared__ unsigned int isLast;
    unsigned int* hist = ctrl;
    const int t = threadIdx.x;

    lh[t] = 0u;
    __syncthreads();
    int tid = blockIdx.x * blockDim.x + t;
    int stride = gridDim.x * blockDim.x;
    int n4 = nnz >> 2;
    const int4* r4 = (const int4*)rows;
    for (int i = tid; i < n4; i += stride) {
        int4 r = r4[i];
        atomicAdd(&lh[(unsigned)r.x >> 13], 1u);
        atomicAdd(&lh[(unsigned)r.y >> 13], 1u);
        atomicAdd(&lh[(unsigned)r.z >> 13], 1u);
        atomicAdd(&lh[(unsigned)r.w >> 13], 1u);
    }
    if (tid == 0)
        for (int i = n4 << 2; i < nnz; ++i) atomicAdd(&hist[(unsigned)rows[i] >> 13], 1u);
    __syncthreads();
    unsigned int v = lh[t];
    if (v) atomicAdd(&hist[t], v);
    __threadfence();
    if (t == 0) isLast = (atomicAdd(&ctrl[770], 1u) == gridDim.x - 1) ? 1u : 0u;
    __syncthreads();
    if (isLast) {
        // exclusive scan over 256 bins -> starts, cursors
        unsigned int hv = atomicAdd(&hist[t], 0u);  // coherent read
        unsigned int inc = hv;
        #pragma unroll
        for (int off = 1; off < 64; off <<= 1) {
            unsigned int n = __shfl_up(inc, off, 64);
            if ((t & 63) >= off) inc += n;
        }
        if ((t & 63) == 63) wsum[t >> 6] = inc;
        __syncthreads();
        unsigned int add = 0;
        for (int i = 0; i < (t >> 6); ++i) add += wsum[i];
        unsigned int excl = inc - hv + add;
        ctrl[256 + t] = excl;   // starts
        ctrl[512 + t] = excl;   // cursors
    }
}

__global__ __launch_bounds__(256) void phaseA_kernel(
    const float* __restrict__ vals, const int* __restrict__ rows,
    const int* __restrict__ cols, const float* __restrict__ x,
    unsigned int* __restrict__ ctrl,
    unsigned int* __restrict__ g_w, int nnz)
{
    __shared__ unsigned int wL[CHUNK];        // 16 KB packed payload
    __shared__ unsigned char bL[CHUNK];       // 4 KB bucket id
    __shared__ unsigned int hist[256], cursor[256];
    __shared__ int gstartI[256];
    __shared__ unsigned int wsum[4];

    unsigned int* gcursor = ctrl + 512;
    const int t = threadIdx.x;
    const long base = (long)blockIdx.x * CHUNK;
    const int cnt = (int)min((long)CHUNK, (long)nnz - base);
    const bool full = (cnt == CHUNK);

    hist[t] = 0u;
    LBAR();                               // hist zero visible

    // ---- issue ALL loads early: cols -> rows -> 16 x-gathers -> vals ----
    int cc[KPT]; int rr[KPT]; float xv[KPT]; float vv[KPT];
    if (full) {
        const int4* c4 = (const int4*)(cols + base);
        #pragma unroll
        for (int k4 = 0; k4 < 4; ++k4) {
            int4 c = c4[t + 256 * k4];
            cc[k4 * 4 + 0] = c.x; cc[k4 * 4 + 1] = c.y;
            cc[k4 * 4 + 2] = c.z; cc[k4 * 4 + 3] = c.w;
        }
        const int4* rows4 = (const int4*)(rows + base);
        #pragma unroll
        for (int k4 = 0; k4 < 4; ++k4) {
            int4 r = rows4[t + 256 * k4];
            rr[k4 * 4 + 0] = r.x; rr[k4 * 4 + 1] = r.y;
            rr[k4 * 4 + 2] = r.z; rr[k4 * 4 + 3] = r.w;
        }
        #pragma unroll
        for (int k = 0; k < KPT; ++k) xv[k] = x[cc[k]];   // 16 gathers in flight
        const float4* v4 = (const float4*)(vals + base);
        #pragma unroll
        for (int k4 = 0; k4 < 4; ++k4) {
            float4 a = v4[t + 256 * k4];
            vv[k4 * 4 + 0] = a.x; vv[k4 * 4 + 1] = a.y;
            vv[k4 * 4 + 2] = a.z; vv[k4 * 4 + 3] = a.w;
        }
    } else {
        #pragma unroll
        for (int k4 = 0; k4 < 4; ++k4)
            #pragma unroll
            for (int j = 0; j < 4; ++j) {
                int idx = (t + 256 * k4) * 4 + j;
                int k = k4 * 4 + j;
                if (idx < cnt) { cc[k] = cols[base + idx]; rr[k] = rows[base + idx]; vv[k] = vals[base + idx]; }
                else { cc[k] = 0; rr[k] = -1; vv[k] = 0.f; }
            }
        #pragma unroll
        for (int k = 0; k < KPT; ++k) xv[k] = x[cc[k]];
    }

    // ---- histogram (consumes rr: vmcnt waits only past cols+rows; gathers
    //      and vals remain outstanding under the LDS work below) ----
    #pragma unroll
    for (int k = 0; k < KPT; ++k)
        if (rr[k] >= 0) atomicAdd(&hist[(unsigned)rr[k] >> 13], 1u);
    LBAR();

    // ---- chunk-local exclusive scan + global slot reservation ----
    unsigned int v = hist[t];
    unsigned int inc = v;
    #pragma unroll
    for (int off = 1; off < 64; off <<= 1) {
        unsigned int n = __shfl_up(inc, off, 64);
        if ((t & 63) >= off) inc += n;
    }
    if ((t & 63) == 63) wsum[t >> 6] = inc;
    LBAR();
    unsigned int add = 0;
    for (int i = 0; i < (t >> 6); ++i) add += wsum[i];
    unsigned int excl = inc - v + add;
    cursor[t] = excl;
    unsigned int gb = v ? atomicAdd(&gcursor[t], v) : 0u;
    gstartI[t] = (int)gb - (int)excl;
    LBAR();

    // ---- pack: p = val*x[col], stage sorted-by-bucket in LDS ----
    #pragma unroll
    for (int k = 0; k < KPT; ++k) {
        int r = rr[k];
        if (r >= 0) {
            float p = vv[k] * xv[k];
            unsigned int bk = (unsigned)r >> 13;
            unsigned int pos = atomicAdd(&cursor[bk], 1u);
            wL[pos] = (__float_as_uint(p) & ~8191u) | ((unsigned)r & 8191u);
            bL[pos] = (unsigned char)bk;
        }
    }
    LBAR();

    // ---- run-structured coalesced flush into bucket-major regions ----
    #pragma unroll
    for (int k = 0; k < KPT; ++k) {
        int i = t + 256 * k;
        if (i < cnt) {
            unsigned int bk = bL[i];
            g_w[gstartI[bk] + i] = wL[i];
        }
    }
}

__global__ __launch_bounds__(1024) void phaseB_kernel(
    const unsigned int* __restrict__ ctrl,
    const unsigned int* __restrict__ g_w,
    float* __restrict__ axh, int NB)
{
    __shared__ float accum[BUCKW];   // 32 KB
    const unsigned int* starts = ctrl + 256;
    const int t = threadIdx.x;
    const int bkt = blockIdx.x >> 1;
    const int h = blockIdx.x & 1;

    for (int i = t; i < BUCKW; i += 1024) accum[i] = 0.f;
    __syncthreads();

    unsigned int s = starts[bkt], e = starts[bkt + 1];
    unsigned int half = (e - s) >> 1;
    unsigned int lo = h ? s + half : s;
    unsigned int hi = h ? e : s + half;

    // head peel to 16B alignment
    unsigned int loA = (lo + 3u) & ~3u;
    if (loA > hi) loA = hi;
    if (lo + t < loA) {
        unsigned int w = g_w[lo + t];
        atomicAdd(&accum[w & 8191u], __uint_as_float(w & ~8191u));
    }
    // vectorized main: uint4, 2-deep
    const uint4* g4 = (const uint4*)g_w;
    unsigned int n4 = (hi - loA) >> 2;
    unsigned int k = (loA >> 2) + t;
    unsigned int kend = (loA >> 2) + n4;
    for (; k + 1024u < kend; k += 2048u) {
        uint4 a = g4[k];
        uint4 c = g4[k + 1024u];
        atomicAdd(&accum[a.x & 8191u], __uint_as_float(a.x & ~8191u));
        atomicAdd(&accum[a.y & 8191u], __uint_as_float(a.y & ~8191u));
        atomicAdd(&accum[a.z & 8191u], __uint_as_float(a.z & ~8191u));
        atomicAdd(&accum[a.w & 8191u], __uint_as_float(a.w & ~8191u));
        atomicAdd(&accum[c.x & 8191u], __uint_as_float(c.x & ~8191u));
        atomicAdd(&accum[c.y & 8191u], __uint_as_float(c.y & ~8191u));
        atomicAdd(&accum[c.z & 8191u], __uint_as_float(c.z & ~8191u));
        atomicAdd(&accum[c.w & 8191u], __uint_as_float(c.w & ~8191u));
    }
    for (; k < kend; k += 1024u) {
        uint4 a = g4[k];
        atomicAdd(&accum[a.x & 8191u], __uint_as_float(a.x & ~8191u));
        atomicAdd(&accum[a.y & 8191u], __uint_as_float(a.y & ~8191u));
        atomicAdd(&accum[a.z & 8191u], __uint_as_float(a.z & ~8191u));
        atomicAdd(&accum[a.w & 8191u], __uint_as_float(a.w & ~8191u));
    }
    // tail scalar
    unsigned int tl = loA + (n4 << 2);
    if (tl + t < hi) {
        unsigned int w = g_w[tl + t];
        atomicAdd(&accum[w & 8191u], __uint_as_float(w & ~8191u));
    }
    __syncthreads();

    // plain coalesced store of partial accumulator into half-slab
    float4* dst = (float4*)(axh + ((size_t)h * NB + bkt) * BUCKW);
    const float4* src = (const float4*)accum;
    for (int i = t; i < BUCKW / 4; i += 1024) dst[i] = src[i];
}

__global__ __launch_bounds__(256) void reduce_kernel(
    const float* __restrict__ axh, const float* __restrict__ bvec,
    const float* __restrict__ iy, unsigned int* __restrict__ ctrl,
    int m, int axstride, float* __restrict__ out)
{
    __shared__ float smp[4], smb[4];
    __shared__ unsigned int isLast;
    unsigned int* maxslots = ctrl + 768;
    const int t = threadIdx.x;
    float mp = 0.f, mb = 0.f;
    int tid = blockIdx.x * blockDim.x + t;
    int stride = gridDim.x * blockDim.x;
    int m4 = m >> 2;
    const float4* a0 = (const float4*)axh;
    const float4* a1 = (const float4*)(axh + axstride);
    const float4* b4 = (const float4*)bvec;
    const float4* g4 = (const float4*)iy;
    for (int i = tid; i < m4; i += stride) {
        float4 u = a0[i], w = a1[i], bb = b4[i], gy = g4[i];
        float y0 = (u.x + w.x) - bb.x, y1 = (u.y + w.y) - bb.y;
        float y2 = (u.z + w.z) - bb.z, y3 = (u.w + w.w) - bb.w;
        float p0 = y0 + gy.x * fmaxf(-y0, 0.f);
        float p1 = y1 + gy.y * fmaxf(-y1, 0.f);
        float p2 = y2 + gy.z * fmaxf(-y2, 0.f);
        float p3 = y3 + gy.w * fmaxf(-y3, 0.f);
        mp = fmaxf(mp, fmaxf(fmaxf(fabsf(p0), fabsf(p1)), fmaxf(fabsf(p2), fabsf(p3))));
        mb = fmaxf(mb, fmaxf(fmaxf(fabsf(bb.x), fabsf(bb.y)), fmaxf(fabsf(bb.z), fabsf(bb.w))));
    }
    for (int i = (m4 << 2) + tid; i < m; i += stride) {
        float bb = bvec[i];
        float y = (axh[i] + axh[axstride + i]) - bb;
        float p = y + iy[i] * fmaxf(-y, 0.f);
        mp = fmaxf(mp, fabsf(p));
        mb = fmaxf(mb, fabsf(bb));
    }
    #pragma unroll
    for (int off = 32; off > 0; off >>= 1) {
        mp = fmaxf(mp, __shfl_down(mp, off, 64));
        mb = fmaxf(mb, __shfl_down(mb, off, 64));
    }
    if ((t & 63) == 0) { smp[t >> 6] = mp; smb[t >> 6] = mb; }
    __syncthreads();
    if (t == 0) {
        #pragma unroll
        for (int w = 1; w < 4; ++w) { mp = fmaxf(mp, smp[w]); mb = fmaxf(mb, smb[w]); }
        atomicMax(&maxslots[0], __float_as_uint(mp));
        atomicMax(&maxslots[1], __float_as_uint(mb));
        __threadfence();
        isLast = (atomicAdd(&ctrl[771], 1u) == gridDim.x - 1) ? 1u : 0u;
    }
    __syncthreads();
    if (isLast && t == 0) {
        float p2 = __uint_as_float(atomicMax(&maxslots[0], 0u));
        float p3 = 1.f + __uint_as_float(atomicMax(&maxslots[1], 0u));
        out[0] = p2 / p3;
    }
}

// ---------- fallback path (tiny ws): direct scatter + reduce ----------
__global__ void fb_zero_kernel(float* __restrict__ ax, unsigned int* __restrict__ maxslots, int m) {
    int tid = blockIdx.x * blockDim.x + threadIdx.x;
    int stride = gridDim.x * blockDim.x;
    int m4 = m >> 2;
    float4* ax4 = reinterpret_cast<float4*>(ax);
    float4 z = make_float4(0.f, 0.f, 0.f, 0.f);
    for (int i = tid; i < m4; i += stride) ax4[i] = z;
    if (tid == 0) {
        for (int j = m4 << 2; j < m; ++j) ax[j] = 0.f;
        maxslots[0] = 0u; maxslots[1] = 0u;
    }
}

__global__ void fb_scatter_kernel(const float* __restrict__ vals, const int* __restrict__ rows,
                                  const int* __restrict__ cols, const float* __restrict__ x,
                                  float* __restrict__ ax, int nnz) {
    int i = (blockIdx.x * blockDim.x + threadIdx.x) << 2;
    if (i + 3 < nnz) {
        float4 v = *reinterpret_cast<const float4*>(vals + i);
        int4 r = *reinterpret_cast<const int4*>(rows + i);
        int4 c = *reinterpret_cast<const int4*>(cols + i);
        atomicAdd(&ax[r.x], v.x * x[c.x]);
        atomicAdd(&ax[r.y], v.y * x[c.y]);
        atomicAdd(&ax[r.z], v.z * x[c.z]);
        atomicAdd(&ax[r.w], v.w * x[c.w]);
    } else {
        for (; i < nnz; ++i) atomicAdd(&ax[rows[i]], vals[i] * x[cols[i]]);
    }
}

__global__ void fb_reduce_kernel(const float* __restrict__ ax, const float* __restrict__ b,
                                 const float* __restrict__ iy, unsigned int* __restrict__ maxslots, int m) {
    float mp = 0.f, mb = 0.f;
    int tid = blockIdx.x * blockDim.x + threadIdx.x;
    int stride = gridDim.x * blockDim.x;
    for (int i = tid; i < m; i += stride) {
        float bb = b[i];
        float y = ax[i] - bb;
        float p = y + iy[i] * fmaxf(-y, 0.f);
        mp = fmaxf(mp, fabsf(p));
        mb = fmaxf(mb, fabsf(bb));
    }
    #pragma unroll
    for (int off = 32; off > 0; off >>= 1) {
        mp = fmaxf(mp, __shfl_down(mp, off, 64));
        mb = fmaxf(mb, __shfl_down(mb, off, 64));
    }
    __shared__ float smp[4], smb[4];
    int wave = threadIdx.x >> 6;
    if ((threadIdx.x & 63) == 0) { smp[wave] = mp; smb[wave] = mb; }
    __syncthreads();
    if (threadIdx.x == 0) {
        for (int w = 1; w < (int)(blockDim.x >> 6); ++w) { mp = fmaxf(mp, smp[w]); mb = fmaxf(mb, smb[w]); }
        atomicMax(&maxslots[0], __float_as_uint(mp));
        atomicMax(&maxslots[1], __float_as_uint(mb));
    }
}

__global__ void fb_finalize_kernel(const unsigned int* __restrict__ maxslots, float* __restrict__ out) {
    if (threadIdx.x == 0 && blockIdx.x == 0) {
        float part2 = __uint_as_float(maxslots[0]);
        float part3 = 1.f + __uint_as_float(maxslots[1]);
        out[0] = part2 / part3;
    }
}

extern "C" void kernel_launch(void* const* d_in, const int* in_sizes, int n_in,
                              void* d_out, int out_size, void* d_ws, size_t ws_size,
                              hipStream_t stream) {
    const float* A_vals = (const float*)d_in[0];
    const float* b      = (const float*)d_in[1];
    // d_in[2] = c : unused
    const float* x      = (const float*)d_in[3];
    const float* Iy     = (const float*)d_in[4];
    const int* A_rows   = (const int*)d_in[5];
    const int* A_cols   = (const int*)d_in[6];

    int nnz = in_sizes[0];
    int m   = in_sizes[1];

    const int NC = (nnz + CHUNK - 1) / CHUNK;
    const int NB = (m + BUCKW - 1) / BUCKW;

    auto al = [](size_t v) { return (v + 255) & ~(size_t)255; };
    size_t ctrlBytes = 4096;
    size_t wOff  = al(ctrlBytes);
    size_t axOff = al(wOff + (size_t)nnz * 4);
    size_t need  = axOff + (size_t)2 * NB * BUCKW * 4;

    float* out = (float*)d_out;

    if (need <= ws_size && NB <= 255 && nnz >= 4) {
        unsigned int* ctrl = (unsigned int*)d_ws;
        unsigned int* g_w  = (unsigned int*)((char*)d_ws + wOff);
        float* axh         = (float*)((char*)d_ws + axOff);

        hipMemsetAsync(ctrl, 0, ctrlBytes, stream);
        precount_kernel<<<1024, 256, 0, stream>>>(A_rows, ctrl, nnz);
        phaseA_kernel<<<NC, 256, 0, stream>>>(A_vals, A_rows, A_cols, x, ctrl, g_w, nnz);
        phaseB_kernel<<<NB * 2, 1024, 0, stream>>>(ctrl, g_w, axh, NB);
        reduce_kernel<<<1024, 256, 0, stream>>>(axh, b, Iy, ctrl, m, NB * BUCKW, out);
    } else {
        float* ax = (float*)d_ws;
        unsigned int* maxslots = (unsigned int*)(ax + m);
        fb_zero_kernel<<<2048, 256, 0, stream>>>(ax, maxslots, m);
        int nthreads = (nnz + 3) >> 2;
        fb_scatter_kernel<<<(nthreads + 255) / 256, 256, 0, stream>>>(A_vals, A_rows, A_cols, x, ax, nnz);
        fb_reduce_kernel<<<2048, 256, 0, stream>>>(ax, b, Iy, maxslots, m);
        fb_finalize_kernel<<<1, 64, 0, stream>>>(maxslots, out);
    }
}

// Round 6
// 392.568 us; speedup vs baseline: 1.2942x; 1.2942x over previous
//
#include <hip/hip_runtime.h>
#include <hip/hip_fp16.h>

// Exact-binned COO segment-sum, bucket-major, single-u32 payload, fp16 x:
//   payload = (float_bits(p) & ~8191) | (local_row & 8191), bucket = row>>13
//   x is pre-converted to fp16 (4 MB) so the random gather hits per-XCD L2.
//
// Pipeline (5 stream ops):
//   memsetAsync(ctrl 4KB)
//   convert   : x f32 -> xh fp16 (4 MB, L2-resident)
//   precount  : exact per-bucket counts; LAST BLOCK does the exclusive scan
//   phaseA    : per-4096-nnz chunk: issue cols/rows/16 xh-gathers/vals early,
//               lgkm-only barriers; LDS counting sort; coalesced run-flush
//   phaseB    : one 1024-thr block per bucket: coalesced region read, LDS f32
//               accumulate, fused proj + inf-norm; LAST BLOCK writes out
//
// ctrl (u32): [0..255] hist | [256..511] starts | [512..767] cursors |
//             [768..769] maxslots | [770] done_precount | [771] done_phaseB
// ws: ctrl 4KB | xh fp16[m] | g_w u32[nnz]

#define CHUNK 4096
#define BUCKW 8192
#define KPT 16

#define LBAR() do { \
    asm volatile("s_waitcnt lgkmcnt(0)" ::: "memory"); \
    __builtin_amdgcn_s_barrier(); \
    asm volatile("" ::: "memory"); \
} while (0)

__global__ __launch_bounds__(256) void convert_kernel(
    const float* __restrict__ x, __half* __restrict__ xh, int n)
{
    int tid = blockIdx.x * blockDim.x + threadIdx.x;
    int stride = gridDim.x * blockDim.x;
    int n8 = n >> 3;
    const float4* x4 = (const float4*)x;
    uint4* out4 = (uint4*)xh;
    for (int i = tid; i < n8; i += stride) {
        float4 a = x4[i * 2];
        float4 b = x4[i * 2 + 1];
        __half2 h0 = __floats2half2_rn(a.x, a.y);
        __half2 h1 = __floats2half2_rn(a.z, a.w);
        __half2 h2 = __floats2half2_rn(b.x, b.y);
        __half2 h3 = __floats2half2_rn(b.z, b.w);
        uint4 o;
        o.x = *reinterpret_cast<unsigned int*>(&h0);
        o.y = *reinterpret_cast<unsigned int*>(&h1);
        o.z = *reinterpret_cast<unsigned int*>(&h2);
        o.w = *reinterpret_cast<unsigned int*>(&h3);
        out4[i] = o;
    }
    if (tid == 0)
        for (int i = n8 << 3; i < n; ++i) xh[i] = __float2half(x[i]);
}

__global__ __launch_bounds__(256) void precount_kernel(
    const int* __restrict__ rows, unsigned int* __restrict__ ctrl, int nnz)
{
    __shared__ unsigned int lh[256];
    __shared__ unsigned int wsum[4];
    __shared__ unsigned int isLast;
    unsigned int* hist = ctrl;
    const int t = threadIdx.x;

    lh[t] = 0u;
    __syncthreads();
    int tid = blockIdx.x * blockDim.x + t;
    int stride = gridDim.x * blockDim.x;
    int n4 = nnz >> 2;
    const int4* r4 = (const int4*)rows;
    for (int i = tid; i < n4; i += stride) {
        int4 r = r4[i];
        atomicAdd(&lh[(unsigned)r.x >> 13], 1u);
        atomicAdd(&lh[(unsigned)r.y >> 13], 1u);
        atomicAdd(&lh[(unsigned)r.z >> 13], 1u);
        atomicAdd(&lh[(unsigned)r.w >> 13], 1u);
    }
    if (tid == 0)
        for (int i = n4 << 2; i < nnz; ++i) atomicAdd(&hist[(unsigned)rows[i] >> 13], 1u);
    __syncthreads();
    unsigned int v = lh[t];
    if (v) atomicAdd(&hist[t], v);
    __threadfence();
    if (t == 0) isLast = (atomicAdd(&ctrl[770], 1u) == gridDim.x - 1) ? 1u : 0u;
    __syncthreads();
    if (isLast) {
        unsigned int hv = atomicAdd(&hist[t], 0u);  // coherent read
        unsigned int inc = hv;
        #pragma unroll
        for (int off = 1; off < 64; off <<= 1) {
            unsigned int n = __shfl_up(inc, off, 64);
            if ((t & 63) >= off) inc += n;
        }
        if ((t & 63) == 63) wsum[t >> 6] = inc;
        __syncthreads();
        unsigned int add = 0;
        for (int i = 0; i < (t >> 6); ++i) add += wsum[i];
        unsigned int excl = inc - hv + add;
        ctrl[256 + t] = excl;   // starts
        ctrl[512 + t] = excl;   // cursors
    }
}

__global__ __launch_bounds__(256) void phaseA_kernel(
    const float* __restrict__ vals, const int* __restrict__ rows,
    const int* __restrict__ cols, const __half* __restrict__ xh,
    unsigned int* __restrict__ ctrl,
    unsigned int* __restrict__ g_w, int nnz)
{
    __shared__ unsigned int wL[CHUNK];        // 16 KB packed payload
    __shared__ unsigned char bL[CHUNK];       // 4 KB bucket id
    __shared__ unsigned int hist[256], cursor[256];
    __shared__ int gstartI[256];
    __shared__ unsigned int wsum[4];

    unsigned int* gcursor = ctrl + 512;
    const int t = threadIdx.x;
    const long base = (long)blockIdx.x * CHUNK;
    const int cnt = (int)min((long)CHUNK, (long)nnz - base);
    const bool full = (cnt == CHUNK);

    hist[t] = 0u;
    LBAR();

    // ---- issue all loads early: cols -> rows -> 16 xh-gathers -> vals ----
    int cc[KPT]; int rr[KPT]; __half xv[KPT]; float vv[KPT];
    if (full) {
        const int4* c4 = (const int4*)(cols + base);
        #pragma unroll
        for (int k4 = 0; k4 < 4; ++k4) {
            int4 c = c4[t + 256 * k4];
            cc[k4 * 4 + 0] = c.x; cc[k4 * 4 + 1] = c.y;
            cc[k4 * 4 + 2] = c.z; cc[k4 * 4 + 3] = c.w;
        }
        const int4* rows4 = (const int4*)(rows + base);
        #pragma unroll
        for (int k4 = 0; k4 < 4; ++k4) {
            int4 r = rows4[t + 256 * k4];
            rr[k4 * 4 + 0] = r.x; rr[k4 * 4 + 1] = r.y;
            rr[k4 * 4 + 2] = r.z; rr[k4 * 4 + 3] = r.w;
        }
        #pragma unroll
        for (int k = 0; k < KPT; ++k) xv[k] = xh[cc[k]];   // 16 L2-hit gathers
        const float4* v4 = (const float4*)(vals + base);
        #pragma unroll
        for (int k4 = 0; k4 < 4; ++k4) {
            float4 a = v4[t + 256 * k4];
            vv[k4 * 4 + 0] = a.x; vv[k4 * 4 + 1] = a.y;
            vv[k4 * 4 + 2] = a.z; vv[k4 * 4 + 3] = a.w;
        }
    } else {
        #pragma unroll
        for (int k4 = 0; k4 < 4; ++k4)
            #pragma unroll
            for (int j = 0; j < 4; ++j) {
                int idx = (t + 256 * k4) * 4 + j;
                int k = k4 * 4 + j;
                if (idx < cnt) { cc[k] = cols[base + idx]; rr[k] = rows[base + idx]; vv[k] = vals[base + idx]; }
                else { cc[k] = 0; rr[k] = -1; vv[k] = 0.f; }
            }
        #pragma unroll
        for (int k = 0; k < KPT; ++k) xv[k] = xh[cc[k]];
    }

    // ---- histogram (consumes rr only; gathers + vals stay in flight) ----
    #pragma unroll
    for (int k = 0; k < KPT; ++k)
        if (rr[k] >= 0) atomicAdd(&hist[(unsigned)rr[k] >> 13], 1u);
    LBAR();

    // ---- chunk-local exclusive scan + global slot reservation ----
    unsigned int v = hist[t];
    unsigned int inc = v;
    #pragma unroll
    for (int off = 1; off < 64; off <<= 1) {
        unsigned int n = __shfl_up(inc, off, 64);
        if ((t & 63) >= off) inc += n;
    }
    if ((t & 63) == 63) wsum[t >> 6] = inc;
    LBAR();
    unsigned int add = 0;
    for (int i = 0; i < (t >> 6); ++i) add += wsum[i];
    unsigned int excl = inc - v + add;
    cursor[t] = excl;
    unsigned int gb = v ? atomicAdd(&gcursor[t], v) : 0u;
    gstartI[t] = (int)gb - (int)excl;
    LBAR();

    // ---- pack: p = val*x[col], stage sorted-by-bucket in LDS ----
    #pragma unroll
    for (int k = 0; k < KPT; ++k) {
        int r = rr[k];
        if (r >= 0) {
            float p = vv[k] * __half2float(xv[k]);
            unsigned int bk = (unsigned)r >> 13;
            unsigned int pos = atomicAdd(&cursor[bk], 1u);
            wL[pos] = (__float_as_uint(p) & ~8191u) | ((unsigned)r & 8191u);
            bL[pos] = (unsigned char)bk;
        }
    }
    LBAR();

    // ---- run-structured coalesced flush into bucket-major regions ----
    #pragma unroll
    for (int k = 0; k < KPT; ++k) {
        int i = t + 256 * k;
        if (i < cnt) {
            unsigned int bk = bL[i];
            g_w[gstartI[bk] + i] = wL[i];
        }
    }
}

__global__ __launch_bounds__(1024) void phaseB_kernel(
    unsigned int* __restrict__ ctrl,
    const unsigned int* __restrict__ g_w,
    const float* __restrict__ bvec, const float* __restrict__ iy,
    int m, float* __restrict__ out)
{
    __shared__ float accum[BUCKW];   // 32 KB
    __shared__ float smp[16], smb[16];
    __shared__ unsigned int isLast;
    const unsigned int* starts = ctrl + 256;
    unsigned int* maxslots = ctrl + 768;
    const int t = threadIdx.x;
    const int bkt = blockIdx.x;

    for (int i = t; i < BUCKW; i += 1024) accum[i] = 0.f;
    __syncthreads();

    const unsigned int s = starts[bkt], e = starts[bkt + 1];
    unsigned int j = s + t;
    for (; j + 7u * 1024u < e; j += 8u * 1024u) {
        unsigned int w0 = g_w[j];
        unsigned int w1 = g_w[j + 1024];
        unsigned int w2 = g_w[j + 2048];
        unsigned int w3 = g_w[j + 3072];
        unsigned int w4 = g_w[j + 4096];
        unsigned int w5 = g_w[j + 5120];
        unsigned int w6 = g_w[j + 6144];
        unsigned int w7 = g_w[j + 7168];
        atomicAdd(&accum[w0 & 8191u], __uint_as_float(w0 & ~8191u));
        atomicAdd(&accum[w1 & 8191u], __uint_as_float(w1 & ~8191u));
        atomicAdd(&accum[w2 & 8191u], __uint_as_float(w2 & ~8191u));
        atomicAdd(&accum[w3 & 8191u], __uint_as_float(w3 & ~8191u));
        atomicAdd(&accum[w4 & 8191u], __uint_as_float(w4 & ~8191u));
        atomicAdd(&accum[w5 & 8191u], __uint_as_float(w5 & ~8191u));
        atomicAdd(&accum[w6 & 8191u], __uint_as_float(w6 & ~8191u));
        atomicAdd(&accum[w7 & 8191u], __uint_as_float(w7 & ~8191u));
    }
    for (; j < e; j += 1024u) {
        unsigned int w = g_w[j];
        atomicAdd(&accum[w & 8191u], __uint_as_float(w & ~8191u));
    }
    __syncthreads();

    // fused projection + inf-norm partial reduce (Ax stays in LDS)
    float mp = 0.f, mb = 0.f;
    long rb = (long)bkt * BUCKW;
    for (int i = t; i < BUCKW; i += 1024) {
        long row = rb + i;
        if (row < m) {
            float a = accum[i];
            float bb = bvec[row];
            float y = a - bb;
            float pr = y + iy[row] * fmaxf(-y, 0.f);
            mp = fmaxf(mp, fabsf(pr));
            mb = fmaxf(mb, fabsf(bb));
        }
    }
    #pragma unroll
    for (int off = 32; off > 0; off >>= 1) {
        mp = fmaxf(mp, __shfl_down(mp, off, 64));
        mb = fmaxf(mb, __shfl_down(mb, off, 64));
    }
    if ((t & 63) == 0) { smp[t >> 6] = mp; smb[t >> 6] = mb; }
    __syncthreads();
    if (t == 0) {
        #pragma unroll
        for (int w = 1; w < 16; ++w) { mp = fmaxf(mp, smp[w]); mb = fmaxf(mb, smb[w]); }
        atomicMax(&maxslots[0], __float_as_uint(mp));
        atomicMax(&maxslots[1], __float_as_uint(mb));
        __threadfence();
        isLast = (atomicAdd(&ctrl[771], 1u) == gridDim.x - 1) ? 1u : 0u;
    }
    __syncthreads();
    if (isLast && t == 0) {
        float p2 = __uint_as_float(atomicMax(&maxslots[0], 0u));
        float p3 = 1.f + __uint_as_float(atomicMax(&maxslots[1], 0u));
        out[0] = p2 / p3;
    }
}

// ---------- fallback path (tiny ws): direct scatter + reduce ----------
__global__ void fb_zero_kernel(float* __restrict__ ax, unsigned int* __restrict__ maxslots, int m) {
    int tid = blockIdx.x * blockDim.x + threadIdx.x;
    int stride = gridDim.x * blockDim.x;
    int m4 = m >> 2;
    float4* ax4 = reinterpret_cast<float4*>(ax);
    float4 z = make_float4(0.f, 0.f, 0.f, 0.f);
    for (int i = tid; i < m4; i += stride) ax4[i] = z;
    if (tid == 0) {
        for (int j = m4 << 2; j < m; ++j) ax[j] = 0.f;
        maxslots[0] = 0u; maxslots[1] = 0u;
    }
}

__global__ void fb_scatter_kernel(const float* __restrict__ vals, const int* __restrict__ rows,
                                  const int* __restrict__ cols, const float* __restrict__ x,
                                  float* __restrict__ ax, int nnz) {
    int i = (blockIdx.x * blockDim.x + threadIdx.x) << 2;
    if (i + 3 < nnz) {
        float4 v = *reinterpret_cast<const float4*>(vals + i);
        int4 r = *reinterpret_cast<const int4*>(rows + i);
        int4 c = *reinterpret_cast<const int4*>(cols + i);
        atomicAdd(&ax[r.x], v.x * x[c.x]);
        atomicAdd(&ax[r.y], v.y * x[c.y]);
        atomicAdd(&ax[r.z], v.z * x[c.z]);
        atomicAdd(&ax[r.w], v.w * x[c.w]);
    } else {
        for (; i < nnz; ++i) atomicAdd(&ax[rows[i]], vals[i] * x[cols[i]]);
    }
}

__global__ void fb_reduce_kernel(const float* __restrict__ ax, const float* __restrict__ b,
                                 const float* __restrict__ iy, unsigned int* __restrict__ maxslots, int m) {
    float mp = 0.f, mb = 0.f;
    int tid = blockIdx.x * blockDim.x + threadIdx.x;
    int stride = gridDim.x * blockDim.x;
    for (int i = tid; i < m; i += stride) {
        float bb = b[i];
        float y = ax[i] - bb;
        float p = y + iy[i] * fmaxf(-y, 0.f);
        mp = fmaxf(mp, fabsf(p));
        mb = fmaxf(mb, fabsf(bb));
    }
    #pragma unroll
    for (int off = 32; off > 0; off >>= 1) {
        mp = fmaxf(mp, __shfl_down(mp, off, 64));
        mb = fmaxf(mb, __shfl_down(mb, off, 64));
    }
    __shared__ float smp[4], smb[4];
    int wave = threadIdx.x >> 6;
    if ((threadIdx.x & 63) == 0) { smp[wave] = mp; smb[wave] = mb; }
    __syncthreads();
    if (threadIdx.x == 0) {
        for (int w = 1; w < (int)(blockDim.x >> 6); ++w) { mp = fmaxf(mp, smp[w]); mb = fmaxf(mb, smb[w]); }
        atomicMax(&maxslots[0], __float_as_uint(mp));
        atomicMax(&maxslots[1], __float_as_uint(mb));
    }
}

__global__ void fb_finalize_kernel(const unsigned int* __restrict__ maxslots, float* __restrict__ out) {
    if (threadIdx.x == 0 && blockIdx.x == 0) {
        float part2 = __uint_as_float(maxslots[0]);
        float part3 = 1.f + __uint_as_float(maxslots[1]);
        out[0] = part2 / part3;
    }
}

extern "C" void kernel_launch(void* const* d_in, const int* in_sizes, int n_in,
                              void* d_out, int out_size, void* d_ws, size_t ws_size,
                              hipStream_t stream) {
    const float* A_vals = (const float*)d_in[0];
    const float* b      = (const float*)d_in[1];
    // d_in[2] = c : unused
    const float* x      = (const float*)d_in[3];
    const float* Iy     = (const float*)d_in[4];
    const int* A_rows   = (const int*)d_in[5];
    const int* A_cols   = (const int*)d_in[6];

    int nnz = in_sizes[0];
    int m   = in_sizes[1];
    int n   = in_sizes[3];

    const int NC = (nnz + CHUNK - 1) / CHUNK;
    const int NB = (m + BUCKW - 1) / BUCKW;

    auto al = [](size_t v) { return (v + 255) & ~(size_t)255; };
    size_t ctrlBytes = 4096;
    size_t xhOff = al(ctrlBytes);
    size_t wOff  = al(xhOff + (size_t)n * 2);
    size_t need  = wOff + (size_t)nnz * 4;

    float* out = (float*)d_out;

    if (need <= ws_size && NB <= 255 && nnz >= 4 && n >= 8) {
        unsigned int* ctrl = (unsigned int*)d_ws;
        __half* xh         = (__half*)((char*)d_ws + xhOff);
        unsigned int* g_w  = (unsigned int*)((char*)d_ws + wOff);

        hipMemsetAsync(ctrl, 0, ctrlBytes, stream);
        convert_kernel<<<977, 256, 0, stream>>>(x, xh, n);
        precount_kernel<<<1024, 256, 0, stream>>>(A_rows, ctrl, nnz);
        phaseA_kernel<<<NC, 256, 0, stream>>>(A_vals, A_rows, A_cols, xh, ctrl, g_w, nnz);
        phaseB_kernel<<<NB, 1024, 0, stream>>>(ctrl, g_w, b, Iy, m, out);
    } else {
        float* ax = (float*)d_ws;
        unsigned int* maxslots = (unsigned int*)(ax + m);
        fb_zero_kernel<<<2048, 256, 0, stream>>>(ax, maxslots, m);
        int nthreads = (nnz + 3) >> 2;
        fb_scatter_kernel<<<(nthreads + 255) / 256, 256, 0, stream>>>(A_vals, A_rows, A_cols, x, ax, nnz);
        fb_reduce_kernel<<<2048, 256, 0, stream>>>(ax, b, Iy, maxslots, m);
        fb_finalize_kernel<<<1, 64, 0, stream>>>(maxslots, out);
    }
}